// Round 1
// baseline (861.422 us; speedup 1.0000x reference)
//
#include <hip/hip_runtime.h>
#include <math.h>

#define B_ 4
#define DIM_ 256
#define H_ 128
#define W_ 128
#define P_ (H_*W_)        // 16384 pixels per batch
#define HEADS_ 8
#define CH_ 32            // channels per head
#define NBH_ (B_*HEADS_)  // 32
#define EPS_ 1e-12f

// ---------------------------------------------------------------------------
// K0: build closed-form kernel table C[s][delta] (the composite
// IFFT_16384 ∘ flatten ∘ FFT2 row operator) and zero the reduction buffers.
// C[s,d] = (1/128) * sum_w exp(2πi w (128 d + s)/16384)
//        = (sin(pi s/128)/sin(pi m/16384)) * e^{i pi (s/128 - m/16384)} / 128
// with m = 128 d + s;  C[0,:] = delta.
// ---------------------------------------------------------------------------
__global__ void k_init(float2* __restrict__ Ctab, float* __restrict__ cross,
                       float* __restrict__ Sq, float* __restrict__ Sk) {
  int i = blockIdx.x * 256 + threadIdx.x;
  if (i < 16384) {
    int s = i >> 7, d = i & 127;
    float2 c;
    if (i == 0) {
      c.x = 1.f; c.y = 0.f;
    } else {
      int m = 128 * d + s;
      float sa = sinpif((float)s / 128.f);
      float sb = sinpif((float)m / 16384.f);
      float mag = sa / (128.f * sb);
      float ang = (float)s / 128.f - (float)m / 16384.f;  // units of pi
      c.x = mag * cospif(ang);
      c.y = mag * sinpif(ang);
    }
    Ctab[i] = c;
  }
  if (i < NBH_ * CH_ * CH_) cross[i] = 0.f;   // 32768
  if (i < B_ * DIM_) { Sq[i] = 0.f; Sk[i] = 0.f; }
}

// ---------------------------------------------------------------------------
// K1: 1x1 conv as GEMM, input layout [b][c][p] (NCHW), OUT[b][o][p].
// Block: 64 o x 128 p, K-tiles of 64.  256 threads, 4ox8p register tile.
// ---------------------------------------------------------------------------
__global__ __launch_bounds__(256) void k_conv_cp(
    const float* __restrict__ X, const float* __restrict__ Wt,
    const float* __restrict__ bias, float* __restrict__ OUT) {
  __shared__ __align__(16) float Xs[64][132];
  __shared__ __align__(16) float Ws[64][68];
  const int tid = threadIdx.x;
  const int p0 = blockIdx.x * 128, o0 = blockIdx.y * 64, b = blockIdx.z;
  const int lp = tid & 15, lo = tid >> 4;
  const float* Xb = X + (size_t)b * DIM_ * P_;
  float acc[4][8];
#pragma unroll
  for (int oi = 0; oi < 4; ++oi) {
    float bv = bias[o0 + lo + 16 * oi];
#pragma unroll
    for (int pp = 0; pp < 8; ++pp) acc[oi][pp] = bv;
  }
  for (int c0 = 0; c0 < DIM_; c0 += 64) {
    {
      int kk = tid >> 2, tq = tid & 3;
      const float* src = Xb + (size_t)(c0 + kk) * P_ + p0;
#pragma unroll
      for (int ii = 0; ii < 8; ++ii) {
        int fi = tq + 4 * ii;
        *(float4*)&Xs[kk][4 * fi] = *(const float4*)(src + 4 * fi);
      }
      const float* wsrc = Wt + (size_t)(o0 + kk) * DIM_ + c0;
#pragma unroll
      for (int ii = 0; ii < 4; ++ii) {
        int fi = tq + 4 * ii;
        *(float4*)&Ws[kk][4 * fi] = *(const float4*)(wsrc + 4 * fi);
      }
    }
    __syncthreads();
#pragma unroll
    for (int kt = 0; kt < 16; ++kt) {
      float4 wf[4];
#pragma unroll
      for (int oi = 0; oi < 4; ++oi)
        wf[oi] = *(const float4*)&Ws[lo + 16 * oi][4 * kt];
      float4 xa[4], xb[4];
#pragma unroll
      for (int kj = 0; kj < 4; ++kj) {
        xa[kj] = *(const float4*)&Xs[4 * kt + kj][4 * lp];
        xb[kj] = *(const float4*)&Xs[4 * kt + kj][64 + 4 * lp];
      }
#pragma unroll
      for (int oi = 0; oi < 4; ++oi) {
#pragma unroll
        for (int kj = 0; kj < 4; ++kj) {
          float w = ((const float*)&wf[oi])[kj];
          acc[oi][0] += w * xa[kj].x;  acc[oi][1] += w * xa[kj].y;
          acc[oi][2] += w * xa[kj].z;  acc[oi][3] += w * xa[kj].w;
          acc[oi][4] += w * xb[kj].x;  acc[oi][5] += w * xb[kj].y;
          acc[oi][6] += w * xb[kj].z;  acc[oi][7] += w * xb[kj].w;
        }
      }
    }
    __syncthreads();
  }
#pragma unroll
  for (int oi = 0; oi < 4; ++oi) {
    float* dst = OUT + (size_t)(b * DIM_ + o0 + lo + 16 * oi) * P_ + p0;
    float4 v0 = make_float4(acc[oi][0], acc[oi][1], acc[oi][2], acc[oi][3]);
    float4 v1 = make_float4(acc[oi][4], acc[oi][5], acc[oi][6], acc[oi][7]);
    *(float4*)(dst + 4 * lp) = v0;
    *(float4*)(dst + 64 + 4 * lp) = v1;
  }
}

// ---------------------------------------------------------------------------
// K4: same GEMM but input layout [b][p][c] (NHWC), OUT[b][o][p].
// Staging transposes the A-tile into LDS.
// ---------------------------------------------------------------------------
__global__ __launch_bounds__(256) void k_conv_nhwc(
    const float* __restrict__ A, const float* __restrict__ Wt,
    const float* __restrict__ bias, float* __restrict__ OUT) {
  __shared__ __align__(16) float Xs[64][132];
  __shared__ __align__(16) float Ws[64][68];
  const int tid = threadIdx.x;
  const int p0 = blockIdx.x * 128, o0 = blockIdx.y * 64, b = blockIdx.z;
  const int lp = tid & 15, lo = tid >> 4;
  float acc[4][8];
#pragma unroll
  for (int oi = 0; oi < 4; ++oi) {
    float bv = bias[o0 + lo + 16 * oi];
#pragma unroll
    for (int pp = 0; pp < 8; ++pp) acc[oi][pp] = bv;
  }
  for (int c0 = 0; c0 < DIM_; c0 += 64) {
    {
      int pr = tid >> 1, cb = (tid & 1) * 32;
      const float* src = A + (size_t)(b * P_ + p0 + pr) * DIM_ + c0 + cb;
#pragma unroll
      for (int q = 0; q < 8; ++q) {
        float4 v = *(const float4*)(src + 4 * q);
        Xs[cb + 4 * q + 0][pr] = v.x;
        Xs[cb + 4 * q + 1][pr] = v.y;
        Xs[cb + 4 * q + 2][pr] = v.z;
        Xs[cb + 4 * q + 3][pr] = v.w;
      }
      int oo = tid >> 2, tq = tid & 3;
      const float* wsrc = Wt + (size_t)(o0 + oo) * DIM_ + c0;
#pragma unroll
      for (int ii = 0; ii < 4; ++ii) {
        int fi = tq + 4 * ii;
        *(float4*)&Ws[oo][4 * fi] = *(const float4*)(wsrc + 4 * fi);
      }
    }
    __syncthreads();
#pragma unroll
    for (int kt = 0; kt < 16; ++kt) {
      float4 wf[4];
#pragma unroll
      for (int oi = 0; oi < 4; ++oi)
        wf[oi] = *(const float4*)&Ws[lo + 16 * oi][4 * kt];
      float4 xa[4], xb[4];
#pragma unroll
      for (int kj = 0; kj < 4; ++kj) {
        xa[kj] = *(const float4*)&Xs[4 * kt + kj][4 * lp];
        xb[kj] = *(const float4*)&Xs[4 * kt + kj][64 + 4 * lp];
      }
#pragma unroll
      for (int oi = 0; oi < 4; ++oi) {
#pragma unroll
        for (int kj = 0; kj < 4; ++kj) {
          float w = ((const float*)&wf[oi])[kj];
          acc[oi][0] += w * xa[kj].x;  acc[oi][1] += w * xa[kj].y;
          acc[oi][2] += w * xa[kj].z;  acc[oi][3] += w * xa[kj].w;
          acc[oi][4] += w * xb[kj].x;  acc[oi][5] += w * xb[kj].y;
          acc[oi][6] += w * xb[kj].z;  acc[oi][7] += w * xb[kj].w;
        }
      }
    }
    __syncthreads();
  }
#pragma unroll
  for (int oi = 0; oi < 4; ++oi) {
    float* dst = OUT + (size_t)(b * DIM_ + o0 + lo + 16 * oi) * P_ + p0;
    float4 v0 = make_float4(acc[oi][0], acc[oi][1], acc[oi][2], acc[oi][3]);
    float4 v1 = make_float4(acc[oi][4], acc[oi][5], acc[oi][6], acc[oi][7]);
    *(float4*)(dst + 4 * lp) = v0;
    *(float4*)(dst + 64 + 4 * lp) = v1;
  }
}

// ---------------------------------------------------------------------------
// K2: per (b,head) compute cross[c][d] = sum_t q[c,t]*k[d,(-t) mod (H,W)]
// plus Sq[c]=sum q^2, Sk[d]=sum k^2 (spatial).  Partial sums via atomics.
// grid: (8 t-chunks, 32 bh), 256 threads, each thread a 2x2 (c,d) tile.
// ---------------------------------------------------------------------------
__global__ __launch_bounds__(256) void k_cross(
    const float* __restrict__ Q, const float* __restrict__ K,
    float* __restrict__ cross, float* __restrict__ Sq, float* __restrict__ Sk) {
  __shared__ __align__(16) float qs[32][132];
  __shared__ __align__(16) float ks[32][132];
  const int tid = threadIdx.x;
  const int chunk = blockIdx.x;   // 0..7
  const int bh = blockIdx.y;      // 0..31
  const int b = bh >> 3, h = bh & 7;
  const size_t base = (size_t)(b * DIM_ + h * CH_) * P_;
  const int i = tid & 15, j = tid >> 4;
  float a00 = 0, a01 = 0, a10 = 0, a11 = 0;
  float sqa = 0, sqb = 0, ska = 0, skb = 0;
  for (int st = 0; st < 16; ++st) {
    int t0 = chunk * 2048 + st * 128;
    {
      int row = tid >> 3, lt = tid & 7;
      const float* src = Q + base + (size_t)row * P_ + t0;
#pragma unroll
      for (int ii = 0; ii < 4; ++ii) {
        int fi = lt + 8 * ii;
        *(float4*)&qs[row][4 * fi] = *(const float4*)(src + 4 * fi);
      }
      const float* ksrc = K + base + (size_t)row * P_;
#pragma unroll
      for (int ii = 0; ii < 16; ++ii) {
        int tt = lt + 8 * ii;
        int t = t0 + tt;
        int y = t >> 7, x = t & 127;
        int ng = ((128 - y) & 127) * 128 + ((128 - x) & 127);
        ks[row][tt] = ksrc[ng];
      }
    }
    __syncthreads();
    for (int tt = 0; tt < 128; ++tt) {
      float qa = qs[i][tt], qb = qs[i + 16][tt];
      float ka = ks[j][tt], kb = ks[j + 16][tt];
      a00 += qa * ka; a01 += qa * kb; a10 += qb * ka; a11 += qb * kb;
      if (j == 0) { sqa += qa * qa; sqb += qb * qb; }
      if (i == 0) { ska += ka * ka; skb += kb * kb; }
    }
    __syncthreads();
  }
  float* cr = cross + bh * 1024;
  atomicAdd(&cr[i * 32 + j], a00);
  atomicAdd(&cr[i * 32 + j + 16], a01);
  atomicAdd(&cr[(i + 16) * 32 + j], a10);
  atomicAdd(&cr[(i + 16) * 32 + j + 16], a11);
  if (j == 0) {
    atomicAdd(&Sq[b * DIM_ + h * CH_ + i], sqa);
    atomicAdd(&Sq[b * DIM_ + h * CH_ + i + 16], sqb);
  }
  if (i == 0) {
    atomicAdd(&Sk[b * DIM_ + h * CH_ + j], ska);
    atomicAdd(&Sk[b * DIM_ + h * CH_ + j + 16], skb);
  }
}

// ---------------------------------------------------------------------------
// K2b: logits -> softmax(real) -> M'[c'][d] = IFFT_32 over c of softmax rows,
// with the uniform softmax(imag=0)=1/32 folded in as M'[0][d] += i/32.
// One block per (b,head).  Output layout Mp[bh][d][c'] (float2).
// ---------------------------------------------------------------------------
__global__ __launch_bounds__(256) void k_attn_m(
    const float* __restrict__ cross, const float* __restrict__ Sq,
    const float* __restrict__ Sk, const float* __restrict__ temp,
    float2* __restrict__ Mp) {
  __shared__ float Ar[32][33];
  __shared__ float ec[32], es[32];
  const int tid = threadIdx.x;
  const int bh = blockIdx.x, b = bh >> 3, h = bh & 7;
  const float tmp = temp[h];
  const float* cr = cross + bh * 1024;
  const float* sq = Sq + b * DIM_ + h * CH_;
  const float* sk = Sk + b * DIM_ + h * CH_;
  const float fN = (float)P_;
#pragma unroll
  for (int ii = 0; ii < 4; ++ii) {
    int idx = tid + 256 * ii;
    int c = idx >> 5, d = idx & 31;
    float nq = fmaxf(sqrtf(fN * sq[c]), EPS_);
    float nk = fmaxf(sqrtf(fN * sk[d]), EPS_);
    Ar[c][d] = cr[idx] * fN / (nq * nk) * tmp;
  }
  if (tid < 32) {
    ec[tid] = cospif((float)tid / 16.f);
    es[tid] = sinpif((float)tid / 16.f);
  }
  __syncthreads();
  if (tid < 32) {
    int c = tid;
    float m = -1e30f;
    for (int d = 0; d < 32; ++d) m = fmaxf(m, Ar[c][d]);
    float ssum = 0.f;
    for (int d = 0; d < 32; ++d) {
      float e = expf(Ar[c][d] - m);
      Ar[c][d] = e; ssum += e;
    }
    float inv = 1.f / ssum;
    for (int d = 0; d < 32; ++d) Ar[c][d] *= inv;
  }
  __syncthreads();
#pragma unroll
  for (int ii = 0; ii < 4; ++ii) {
    int idx = tid + 256 * ii;
    int d2 = idx >> 5, c2 = idx & 31;
    float re = 0.f, im = 0.f;
    for (int c = 0; c < 32; ++c) {
      float a = Ar[c][d2];
      int k = (c * c2) & 31;
      re += a * ec[k]; im += a * es[k];
    }
    re *= (1.f / 32.f); im *= (1.f / 32.f);
    if (c2 == 0) im += (1.f / 32.f);
    Mp[bh * 1024 + idx] = make_float2(re, im);
  }
}

// ---------------------------------------------------------------------------
// K3: per (b,head,s): G[d][r] = sum_x C[s][(r-x)&127] * v[d][s][x]   (complex)
// then final[c'][r] = sum_d M'[c'][d] * G[d][r]; write |final| to NHWC buffer
// ABS[b][r*128+s][h*32+c'].
// ---------------------------------------------------------------------------
__global__ __launch_bounds__(256) void k_main(
    const float* __restrict__ V, const float2* __restrict__ Ctab,
    const float2* __restrict__ Mp, float* __restrict__ ABS) {
  __shared__ __align__(16) float vv[32][128];
  __shared__ __align__(16) float2 G2[32 * 128];
  __shared__ __align__(16) float2 crow[128];
  __shared__ __align__(16) float2 Mlds[32 * 33];
  const int tid = threadIdx.x;
  const int s = blockIdx.x, h = blockIdx.y, b = blockIdx.z;
  const int bh = b * HEADS_ + h;
  {
    int d = tid >> 3, lt = tid & 7;
    const float* src = V + (size_t)(b * DIM_ + h * CH_ + d) * P_ + s * W_;
#pragma unroll
    for (int ii = 0; ii < 4; ++ii) {
      int fi = lt + 8 * ii;
      *(float4*)&vv[d][4 * fi] = *(const float4*)(src + 4 * fi);
    }
  }
  if (tid < 64) {
    ((float4*)crow)[tid] = ((const float4*)(Ctab + s * 128))[tid];
  }
#pragma unroll
  for (int ii = 0; ii < 4; ++ii) {
    int idx = tid + 256 * ii;
    int d = idx >> 5, c2 = idx & 31;
    Mlds[d * 33 + c2] = Mp[bh * 1024 + idx];
  }
  __syncthreads();
  {
    const int rgrp = tid & 31, dgrp = tid >> 5;
    float ar[4][4], ai[4][4];
#pragma unroll
    for (int dd = 0; dd < 4; ++dd)
#pragma unroll
      for (int rr = 0; rr < 4; ++rr) { ar[dd][rr] = 0.f; ai[dd][rr] = 0.f; }
    for (int x = 0; x < 128; ++x) {
      float vx[4];
#pragma unroll
      for (int dd = 0; dd < 4; ++dd) vx[dd] = vv[dgrp + 8 * dd][x];
#pragma unroll
      for (int rr = 0; rr < 4; ++rr) {
        float2 cv = crow[(rgrp + 32 * rr - x) & 127];
#pragma unroll
        for (int dd = 0; dd < 4; ++dd) {
          ar[dd][rr] += vx[dd] * cv.x;
          ai[dd][rr] += vx[dd] * cv.y;
        }
      }
    }
#pragma unroll
    for (int dd = 0; dd < 4; ++dd)
#pragma unroll
      for (int rr = 0; rr < 4; ++rr)
        G2[(dgrp + 8 * dd) * 128 + rgrp + 32 * rr] =
            make_float2(ar[dd][rr], ai[dd][rr]);
  }
  __syncthreads();
  {
    const int c2 = tid & 31, rb = tid >> 5;
    float aR[16], aI[16];
#pragma unroll
    for (int it = 0; it < 16; ++it) { aR[it] = 0.f; aI[it] = 0.f; }
    for (int d = 0; d < 32; ++d) {
      float2 m = Mlds[d * 33 + c2];
#pragma unroll
      for (int it = 0; it < 16; ++it) {
        float2 g = G2[d * 128 + rb + 8 * it];
        aR[it] += m.x * g.x - m.y * g.y;
        aI[it] += m.x * g.y + m.y * g.x;
      }
    }
    float* dst = ABS + (size_t)b * P_ * DIM_ + h * CH_ + c2;
#pragma unroll
    for (int it = 0; it < 16; ++it) {
      int r = rb + 8 * it;
      dst[(size_t)(r * W_ + s) * DIM_] = sqrtf(aR[it] * aR[it] + aI[it] * aI[it]);
    }
  }
}

// ---------------------------------------------------------------------------
extern "C" void kernel_launch(void* const* d_in, const int* in_sizes, int n_in,
                              void* d_out, int out_size, void* d_ws,
                              size_t ws_size, hipStream_t stream) {
  const float* x  = (const float*)d_in[0];
  const float* w1 = (const float*)d_in[1];
  const float* b1 = (const float*)d_in[2];
  const float* w2 = (const float*)d_in[3];
  const float* b2 = (const float*)d_in[4];
  const float* w3 = (const float*)d_in[5];
  const float* b3 = (const float*)d_in[6];
  const float* wo = (const float*)d_in[7];
  const float* bo = (const float*)d_in[8];
  const float* temp = (const float*)d_in[9];
  float* out = (float*)d_out;

  const size_t TEN = (size_t)B_ * DIM_ * P_;  // 16,777,216 floats
  float* wsf  = (float*)d_ws;
  float* v_s  = wsf;
  float* q_s  = wsf + TEN;          // later aliased by ABS (q dead after k_cross)
  float* k_s  = wsf + 2 * TEN;
  float* tail = wsf + 3 * TEN;
  float2* Ctab = (float2*)tail;                 // 16384 float2
  float* cross = tail + 2 * 16384;              // 32768 floats
  float* Sq    = cross + 32768;                 // 1024
  float* Sk    = Sq + 1024;                     // 1024
  float2* Mp   = (float2*)(Sk + 1024);          // 16384 float2
  float* ABS   = q_s;

  k_init<<<dim3(128), dim3(256), 0, stream>>>(Ctab, cross, Sq, Sk);
  k_conv_cp<<<dim3(128, 4, B_), dim3(256), 0, stream>>>(x, w1, b1, q_s);
  k_conv_cp<<<dim3(128, 4, B_), dim3(256), 0, stream>>>(x, w2, b2, k_s);
  k_conv_cp<<<dim3(128, 4, B_), dim3(256), 0, stream>>>(x, w3, b3, v_s);
  k_cross<<<dim3(8, 32), dim3(256), 0, stream>>>(q_s, k_s, cross, Sq, Sk);
  k_attn_m<<<dim3(32), dim3(256), 0, stream>>>(cross, Sq, Sk, temp, Mp);
  k_main<<<dim3(128, 8, B_), dim3(256), 0, stream>>>(v_s, Ctab, Mp, ABS);
  k_conv_nhwc<<<dim3(128, 4, B_), dim3(256), 0, stream>>>(ABS, wo, bo, out);
}